// Round 5
// baseline (396.208 us; speedup 1.0000x reference)
//
#include <hip/hip_runtime.h>
#include <hip/hip_cooperative_groups.h>
#include <math.h>

namespace cg = cooperative_groups;

#define BB   64
#define NN   1024
#define FIN  16
#define DIM  64
#define KK   20
#define EPSV 1e-5f
#define SLOPE 0.2f
#define BN_COUNT (BB*NN)
#define REPS 16
#define NBLK 512   // 2 blocks/CU, co-resident (<=256 VGPR, 8.5KB LDS)

__device__ inline float wred_sum(float v){
  #pragma unroll
  for (int m = 32; m > 0; m >>= 1) v += __shfl_xor(v, m, 64);
  return v;
}

// top-20 selection over cosv[1024] by one wave; 16 values register-resident
// per lane; strict > keeps lowest index on ties (lax.top_k semantics).
__device__ inline void select20(const float* cosv, int* topk_row, int lane){
  float c[16];
  #pragma unroll
  for (int q = 0; q < 4; q++){
    float4 v = ((const float4*)cosv)[lane*4 + q];
    c[q*4+0] = v.x; c[q*4+1] = v.y; c[q*4+2] = v.z; c[q*4+3] = v.w;
  }
  #pragma unroll 1
  for (int k = 0; k < KK; k++){
    float bv = c[0]; int bm = 0;
    #pragma unroll
    for (int m = 1; m < 16; m++){
      if (c[m] > bv){ bv = c[m]; bm = m; }
    }
    int bj = lane*16 + bm;
    #pragma unroll
    for (int msk = 32; msk > 0; msk >>= 1){
      float pv = __shfl_xor(bv, msk, 64);
      int   pj = __shfl_xor(bj, msk, 64);
      if (pv > bv || (pv == bv && pj < bj)){ bv = pv; bj = pj; }
    }
    if (lane == 0) topk_row[k] = bj;
    #pragma unroll
    for (int m = 0; m < 16; m++){
      c[m] = (bj == lane*16 + m) ? -1e30f : c[m];
    }
  }
}

__global__ __launch_bounds__(256, 2)
void mega(const float* __restrict__ data, const float* __restrict__ emb,
          const float* __restrict__ lin_w,
          const float* __restrict__ att_i, const float* __restrict__ att_j,
          const float* __restrict__ att_em_i, const float* __restrict__ att_em_j,
          const float* __restrict__ gnn_bias,
          const float* __restrict__ bn1_g, const float* __restrict__ bn1_b,
          const float* __restrict__ bn2_g, const float* __restrict__ bn2_b,
          const float* __restrict__ out_w, const float* __restrict__ out_b,
          float* __restrict__ out,
          float* __restrict__ h, float* __restrict__ outp,
          float* __restrict__ s_i, float* __restrict__ s_j,
          int* __restrict__ topk, float* __restrict__ acc1){
  cg::grid_group grid = cg::this_grid();
  __shared__ float smem[2112];          // 2 x cosv[1024] + embi[64]
  float* acc2 = acc1 + REPS*128;
  int t = threadIdx.x, p = blockIdx.x;
  int wave = t >> 6, lane = t & 63;

  // zero BN accumulators (visible after grid.sync #1)
  if (p == 0){
    for (int u = t; u < 2*REPS*128; u += 256) acc1[u] = 0.f;
  }

  // ================= S1: cosine keys + top-20 for rows p*2, p*2+1 ========
  {
    float* embi = smem + 2048;
    int g = t >> 4, l16 = t & 15;
    const float4* e4 = (const float4*)emb;
    #pragma unroll 1
    for (int ii = 0; ii < 2; ii++){
      int i = p*2 + ii;
      float* cosv = smem + ii*1024;
      if (t < DIM) embi[t] = emb[i*DIM + t];
      __syncthreads();
      float4 a4 = ((const float4*)embi)[l16];
      #pragma unroll 1
      for (int jb = 0; jb < NN; jb += 16){
        int j = jb + g;
        float4 b4 = e4[j*(DIM/4) + l16];
        float pd = a4.x*b4.x + a4.y*b4.y + a4.z*b4.z + a4.w*b4.w;
        float nj = b4.x*b4.x + b4.y*b4.y + b4.z*b4.z + b4.w*b4.w;
        pd += __shfl_xor(pd, 1, 64); nj += __shfl_xor(nj, 1, 64);
        pd += __shfl_xor(pd, 2, 64); nj += __shfl_xor(nj, 2, 64);
        pd += __shfl_xor(pd, 4, 64); nj += __shfl_xor(nj, 4, 64);
        pd += __shfl_xor(pd, 8, 64); nj += __shfl_xor(nj, 8, 64);
        // key = dot / |w_j| : same top-k order as cos (missing 1/|w_i| is a
        // positive per-row constant)
        if (l16 == 0) cosv[j] = pd * rsqrtf(nj);
      }
      __syncthreads();   // embi reload next iter / cosv complete
    }
    // waves 0 and 1 select for the two rows in parallel
    if (wave < 2) select20(smem + wave*1024, topk + (p*2 + wave)*KK, lane);
    __syncthreads();     // smem free for S2
  }

  // ================= S2: h = data @ lin_w^T ; s_i, s_j ===================
  {
    float* lw  = smem;          // [f*64+d]
    float* sdm = smem + 1024;   // 16 rows x 16 f
    for (int u = t; u < FIN*DIM; u += 256){
      int d = u >> 4, f = u & 15;
      lw[f*DIM + d] = lin_w[u];
    }
    float ai = att_i[lane], aj = att_j[lane];
    float aemi = att_em_i[lane], aemj = att_em_j[lane];
    #pragma unroll 1
    for (int tile = 0; tile < 8; tile++){
      int r0 = p*128 + tile*16;
      __syncthreads();
      sdm[t] = data[r0*FIN + t];
      __syncthreads();
      #pragma unroll
      for (int q = 0; q < 4; q++){
        int row = wave*4 + q;
        int r = r0 + row;
        int n = r & (NN-1);
        float acc = 0.f;
        #pragma unroll
        for (int f4 = 0; f4 < 4; f4++){
          float4 d4 = ((const float4*)(sdm + row*FIN))[f4];
          acc += d4.x * lw[(f4*4+0)*DIM + lane];
          acc += d4.y * lw[(f4*4+1)*DIM + lane];
          acc += d4.z * lw[(f4*4+2)*DIM + lane];
          acc += d4.w * lw[(f4*4+3)*DIM + lane];
        }
        h[r*DIM + lane] = acc;
        float ev = emb[n*DIM + lane];
        float si = wred_sum(acc*ai + ev*aemi);
        float sj = wred_sum(acc*aj + ev*aemj);
        if (lane == 0){ s_i[r] = si; s_j[r] = sj; }
      }
    }
  }

  grid.sync();   // h, s_i, s_j, topk, acc zeroing all visible

  // ================= S3: softmax-K + gather + BN1 stats ==================
  {
    float* chs = smem; float* chq = smem + 64;
    if (t < 128) smem[t] = 0.f;
    __syncthreads();
    int xcd = p & 7, slot = p >> 3;
    int b = xcd + 8*(slot & 7);        // 8 batches per XCD -> 2MB L2 set
    int chunk = slot >> 3;             // 0..7 : 128 rows
    int rs = lane >> 4, cg16 = lane & 15;
    const float* hb  = h   + (size_t)b * NN * DIM;
    const float* sjb = s_j + (size_t)b * NN;
    float4 gb4 = *(const float4*)(gnn_bias + cg16*4);
    float ps0=0,ps1=0,ps2=0,ps3=0,pq0=0,pq1=0,pq2=0,pq3=0;
    #pragma unroll 1
    for (int it = 0; it < 8; it++){
      int n = chunk*128 + it*16 + wave*4 + rs;
      float siv = s_i[(size_t)b*NN + n];
      int idx[KK];
      #pragma unroll
      for (int k = 0; k < KK; k++) idx[k] = topk[n*KK + k];
      __builtin_amdgcn_sched_barrier(0);
      float sjv[KK];
      #pragma unroll
      for (int k = 0; k < KK; k++) sjv[k] = sjb[idx[k]];
      float4 gv[KK];
      #pragma unroll
      for (int k = 0; k < KK; k++) gv[k] = *(const float4*)(hb + idx[k]*DIM + cg16*4);
      __builtin_amdgcn_sched_barrier(0);
      float xv[KK];
      #pragma unroll
      for (int k = 0; k < KK; k++){
        float x = siv + sjv[k];
        xv[k] = (x > 0.f) ? x : SLOPE * x;
      }
      float m = xv[0];
      #pragma unroll
      for (int k = 1; k < KK; k++) m = fmaxf(m, xv[k]);
      float ssum = 0.f;
      #pragma unroll
      for (int k = 0; k < KK; k++){ xv[k] = __expf(xv[k] - m); ssum += xv[k]; }
      float rinv = 1.f / ssum;
      float4 o = {0.f,0.f,0.f,0.f};
      #pragma unroll
      for (int k = 0; k < KK; k++){
        float a = xv[k]*rinv;
        o.x += a*gv[k].x; o.y += a*gv[k].y; o.z += a*gv[k].z; o.w += a*gv[k].w;
      }
      o.x += gb4.x; o.y += gb4.y; o.z += gb4.z; o.w += gb4.w;
      *(float4*)(outp + ((size_t)b*NN + n)*DIM + cg16*4) = o;
      ps0 += o.x; pq0 += o.x*o.x;
      ps1 += o.y; pq1 += o.y*o.y;
      ps2 += o.z; pq2 += o.z*o.z;
      ps3 += o.w; pq3 += o.w*o.w;
    }
    int c0 = cg16*4;
    atomicAdd(&chs[c0+0], ps0); atomicAdd(&chq[c0+0], pq0);
    atomicAdd(&chs[c0+1], ps1); atomicAdd(&chq[c0+1], pq1);
    atomicAdd(&chs[c0+2], ps2); atomicAdd(&chq[c0+2], pq2);
    atomicAdd(&chs[c0+3], ps3); atomicAdd(&chq[c0+3], pq3);
    __syncthreads();
    float* accr = acc1 + (p & (REPS-1))*128;
    if (t < DIM){ atomicAdd(&accr[t], chs[t]); atomicAdd(&accr[64+t], chq[t]); }
  }

  grid.sync();   // BN1 stats complete

  // ================= S4: BN1 apply + relu + *emb -> rep ; BN2 stats ======
  {
    float* chs = smem; float* chq = smem + 64;
    if (t < 128) smem[t] = 0.f;
    __syncthreads();
    int cbase = (t*4) & 63;
    float4 sm = {0,0,0,0}, sq = {0,0,0,0};
    #pragma unroll
    for (int rp = 0; rp < REPS; rp++){
      float4 a = *(const float4*)(acc1 + rp*128 + cbase);
      float4 b = *(const float4*)(acc1 + rp*128 + 64 + cbase);
      sm.x += a.x; sm.y += a.y; sm.z += a.z; sm.w += a.w;
      sq.x += b.x; sq.y += b.y; sq.z += b.z; sq.w += b.w;
    }
    float4 sc, bs;
    {
      const float inv = 1.f / BN_COUNT;
      float m0 = sm.x*inv, m1 = sm.y*inv, m2 = sm.z*inv, m3 = sm.w*inv;
      float v0 = sq.x*inv - m0*m0, v1 = sq.y*inv - m1*m1;
      float v2 = sq.z*inv - m2*m2, v3 = sq.w*inv - m3*m3;
      sc.x = bn1_g[cbase+0]*rsqrtf(v0+EPSV); sc.y = bn1_g[cbase+1]*rsqrtf(v1+EPSV);
      sc.z = bn1_g[cbase+2]*rsqrtf(v2+EPSV); sc.w = bn1_g[cbase+3]*rsqrtf(v3+EPSV);
      bs.x = bn1_b[cbase+0] - m0*sc.x; bs.y = bn1_b[cbase+1] - m1*sc.y;
      bs.z = bn1_b[cbase+2] - m2*sc.z; bs.w = bn1_b[cbase+3] - m3*sc.w;
    }
    float s0=0,s1=0,s2=0,s3=0,q0=0,q1=0,q2=0,q3=0;
    const float4* op4 = (const float4*)outp;
    const float4* em4 = (const float4*)emb;
    float4* rp4 = (float4*)h;            // rep aliases h (dead after S3)
    const int total = BB*NN*DIM/4;
    for (int e = p*256 + t; e < total; e += NBLK*256){
      float4 x = op4[e];
      float4 em = em4[e & (NN*DIM/4 - 1)];
      float4 y;
      y.x = fmaxf(x.x*sc.x + bs.x, 0.f) * em.x;
      y.y = fmaxf(x.y*sc.y + bs.y, 0.f) * em.y;
      y.z = fmaxf(x.z*sc.z + bs.z, 0.f) * em.z;
      y.w = fmaxf(x.w*sc.w + bs.w, 0.f) * em.w;
      rp4[e] = y;
      s0 += y.x; q0 += y.x*y.x;
      s1 += y.y; q1 += y.y*y.y;
      s2 += y.z; q2 += y.z*y.z;
      s3 += y.w; q3 += y.w*y.w;
    }
    atomicAdd(&chs[cbase+0], s0); atomicAdd(&chq[cbase+0], q0);
    atomicAdd(&chs[cbase+1], s1); atomicAdd(&chq[cbase+1], q1);
    atomicAdd(&chs[cbase+2], s2); atomicAdd(&chq[cbase+2], q2);
    atomicAdd(&chs[cbase+3], s3); atomicAdd(&chq[cbase+3], q3);
    __syncthreads();
    float* acc2r = acc2 + (p & (REPS-1))*128;
    if (t < DIM){ atomicAdd(&acc2r[t], chs[t]); atomicAdd(&acc2r[64+t], chq[t]); }
  }

  grid.sync();   // BN2 stats complete

  // ================= S5: BN2 apply + relu + dot(out_w) -> out ============
  {
    int c16 = lane & 15, rsub = lane >> 4;
    int cb = c16*4;
    float4 sm = {0,0,0,0}, sq = {0,0,0,0};
    #pragma unroll
    for (int rp = 0; rp < REPS; rp++){
      float4 a = *(const float4*)(acc2 + rp*128 + cb);
      float4 b = *(const float4*)(acc2 + rp*128 + 64 + cb);
      sm.x += a.x; sm.y += a.y; sm.z += a.z; sm.w += a.w;
      sq.x += b.x; sq.y += b.y; sq.z += b.z; sq.w += b.w;
    }
    float4 sc, bs;
    {
      const float inv = 1.f / BN_COUNT;
      float m0 = sm.x*inv, m1 = sm.y*inv, m2 = sm.z*inv, m3 = sm.w*inv;
      float v0 = sq.x*inv - m0*m0, v1 = sq.y*inv - m1*m1;
      float v2 = sq.z*inv - m2*m2, v3 = sq.w*inv - m3*m3;
      sc.x = bn2_g[cb+0]*rsqrtf(v0+EPSV); sc.y = bn2_g[cb+1]*rsqrtf(v1+EPSV);
      sc.z = bn2_g[cb+2]*rsqrtf(v2+EPSV); sc.w = bn2_g[cb+3]*rsqrtf(v3+EPSV);
      bs.x = bn2_b[cb+0] - m0*sc.x; bs.y = bn2_b[cb+1] - m1*sc.y;
      bs.z = bn2_b[cb+2] - m2*sc.z; bs.w = bn2_b[cb+3] - m3*sc.w;
    }
    float4 w4 = *(const float4*)(out_w + cb);
    float ob = out_b[0];
    const float* rep = h;
    int rbase = p*128 + wave*32;
    #pragma unroll 1
    for (int i = 0; i < 32; i += 4){
      int r = rbase + i + rsub;
      float4 x = *(const float4*)(rep + (size_t)r*DIM + cb);
      float pr = fmaxf(x.x*sc.x + bs.x, 0.f) * w4.x
               + fmaxf(x.y*sc.y + bs.y, 0.f) * w4.y
               + fmaxf(x.z*sc.z + bs.z, 0.f) * w4.z
               + fmaxf(x.w*sc.w + bs.w, 0.f) * w4.w;
      pr += __shfl_xor(pr, 1, 64); pr += __shfl_xor(pr, 2, 64);
      pr += __shfl_xor(pr, 4, 64); pr += __shfl_xor(pr, 8, 64);
      if (c16 == 0) out[r] = pr + ob;
    }
  }
}

extern "C" void kernel_launch(void* const* d_in, const int* in_sizes, int n_in,
                              void* d_out, int out_size, void* d_ws, size_t ws_size,
                              hipStream_t stream) {
  const float* data     = (const float*)d_in[0];
  const float* emb      = (const float*)d_in[2];
  const float* lin_w    = (const float*)d_in[3];
  const float* att_i    = (const float*)d_in[4];
  const float* att_j    = (const float*)d_in[5];
  const float* att_em_i = (const float*)d_in[6];
  const float* att_em_j = (const float*)d_in[7];
  const float* gnn_bias = (const float*)d_in[8];
  const float* bn1_g    = (const float*)d_in[9];
  const float* bn1_b    = (const float*)d_in[10];
  const float* bn2_g    = (const float*)d_in[11];
  const float* bn2_b    = (const float*)d_in[12];
  const float* out_w    = (const float*)d_in[13];
  const float* out_b    = (const float*)d_in[14];
  float* out = (float*)d_out;

  float* ws   = (float*)d_ws;
  float* h    = ws;                        // 4194304 floats (rep aliases)
  float* outp = ws + 4194304;              // 4194304
  float* s_i  = ws + 8388608;              // 65536
  float* s_j  = s_i + 65536;               // 65536
  int*   topk = (int*)(s_j + 65536);       // 20480 ints
  float* acc1 = (float*)(topk + NN*KK);    // 2*REPS*128 floats

  void* args[] = {
    (void*)&data, (void*)&emb, (void*)&lin_w, (void*)&att_i, (void*)&att_j,
    (void*)&att_em_i, (void*)&att_em_j, (void*)&gnn_bias,
    (void*)&bn1_g, (void*)&bn1_b, (void*)&bn2_g, (void*)&bn2_b,
    (void*)&out_w, (void*)&out_b, (void*)&out,
    (void*)&h, (void*)&outp, (void*)&s_i, (void*)&s_j,
    (void*)&topk, (void*)&acc1
  };
  hipLaunchCooperativeKernel((void*)mega, dim3(NBLK), dim3(256), args, 0, stream);
}

// Round 6
// 217.509 us; speedup vs baseline: 1.8216x; 1.8216x over previous
//
#include <hip/hip_runtime.h>
#include <math.h>

#define BB   64
#define NN   1024
#define FIN  16
#define DIM  64
#define KK   20
#define EPSV 1e-5f
#define SLOPE 0.2f
#define BN_COUNT (BB*NN)
#define REPS 16

__device__ inline float wred_sum(float v){
  #pragma unroll
  for (int m = 32; m > 0; m >>= 1) v += __shfl_xor(v, m, 64);
  return v;
}

// ---------------- kB: cosine keys + top-20 (lax.top_k semantics) ---------
// key = dot(w_i,w_j)/|w_j| — same order as cosine (1/|w_i| is a positive
// per-row constant). Block 0 also zeroes the BN accumulators.
__global__ void kB(const float* __restrict__ emb, int* __restrict__ topk,
                   float* __restrict__ accz){
  __shared__ float cosv[NN];
  __shared__ __align__(16) float embi[DIM];
  int i = blockIdx.x, t = threadIdx.x;
  if (i == 0){
    for (int u = t; u < 2*REPS*128; u += 256) accz[u] = 0.f;
  }
  if (t < DIM) embi[t] = emb[i*DIM + t];
  __syncthreads();
  int g = t >> 4, l16 = t & 15;
  const float4* e4 = (const float4*)emb;
  float4 a4 = ((const float4*)embi)[l16];
  #pragma unroll 1
  for (int jb = 0; jb < NN; jb += 16){
    int j = jb + g;
    float4 b4 = e4[j*(DIM/4) + l16];
    float pd = a4.x*b4.x + a4.y*b4.y + a4.z*b4.z + a4.w*b4.w;
    float nj = b4.x*b4.x + b4.y*b4.y + b4.z*b4.z + b4.w*b4.w;
    pd += __shfl_xor(pd, 1, 64); nj += __shfl_xor(nj, 1, 64);
    pd += __shfl_xor(pd, 2, 64); nj += __shfl_xor(nj, 2, 64);
    pd += __shfl_xor(pd, 4, 64); nj += __shfl_xor(nj, 4, 64);
    pd += __shfl_xor(pd, 8, 64); nj += __shfl_xor(nj, 8, 64);
    if (l16 == 0) cosv[j] = pd * rsqrtf(nj);
  }
  __syncthreads();
  if (t < 64){
    float c[16];
    #pragma unroll
    for (int q = 0; q < 4; q++){
      float4 v = ((const float4*)cosv)[t*4 + q];
      c[q*4+0] = v.x; c[q*4+1] = v.y; c[q*4+2] = v.z; c[q*4+3] = v.w;
    }
    #pragma unroll 1
    for (int k = 0; k < KK; k++){
      float bv = c[0]; int bm = 0;
      #pragma unroll
      for (int m = 1; m < 16; m++){
        if (c[m] > bv){ bv = c[m]; bm = m; }   // strict > : lowest idx wins ties
      }
      int bj = t*16 + bm;
      #pragma unroll
      for (int msk = 32; msk > 0; msk >>= 1){
        float pv = __shfl_xor(bv, msk, 64);
        int   pj = __shfl_xor(bj, msk, 64);
        if (pv > bv || (pv == bv && pj < bj)){ bv = pv; bj = pj; }
      }
      if (t == 0) topk[i*KK + k] = bj;
      #pragma unroll
      for (int m = 0; m < 16; m++){
        c[m] = (bj == t*16 + m) ? -1e30f : c[m];
      }
    }
  }
}

// ---------------- kC: h = data @ lin_w^T ; s_i, s_j (incl. emb terms) ----
__global__ void kC(const float* __restrict__ data, const float* __restrict__ lin_w,
                   const float* __restrict__ att_i, const float* __restrict__ att_j,
                   const float* __restrict__ att_em_i, const float* __restrict__ att_em_j,
                   const float* __restrict__ emb,
                   float* __restrict__ h, float* __restrict__ s_i, float* __restrict__ s_j){
  __shared__ float lw[FIN*DIM];              // lw[f*64+d]
  __shared__ __align__(16) float sd[16][FIN];
  int t = threadIdx.x;
  for (int u = t; u < FIN*DIM; u += 256){
    int d = u >> 4, f = u & 15;
    lw[f*DIM + d] = lin_w[u];
  }
  int r0 = blockIdx.x*16;
  sd[t >> 4][t & 15] = data[r0*FIN + t];
  __syncthreads();
  int wave = t >> 6, lane = t & 63;
  float ai = att_i[lane], aj = att_j[lane];
  float aemi = att_em_i[lane], aemj = att_em_j[lane];
  #pragma unroll
  for (int q = 0; q < 4; q++){
    int row = wave*4 + q;
    int r = r0 + row;
    int n = r & (NN-1);
    float acc = 0.f;
    #pragma unroll
    for (int f4 = 0; f4 < 4; f4++){
      float4 d4 = ((const float4*)sd[row])[f4];
      acc += d4.x * lw[(f4*4+0)*DIM + lane];
      acc += d4.y * lw[(f4*4+1)*DIM + lane];
      acc += d4.z * lw[(f4*4+2)*DIM + lane];
      acc += d4.w * lw[(f4*4+3)*DIM + lane];
    }
    h[r*DIM + lane] = acc;
    float ev = emb[n*DIM + lane];
    float si = wred_sum(acc*ai + ev*aemi);
    float sj = wred_sum(acc*aj + ev*aemj);
    if (lane == 0){ s_i[r] = si; s_j[r] = sj; }
  }
}

// ------- kD: wave-per-row softmax-K + gather + BN1 stats -----------------
// n is wave-uniform -> topk/s_j/s_i loads scalarize (SMEM pipe); only the
// 20 h-row gathers (256B coalesced dword/wave) + 1 store hit VMEM.
// XCD-swizzled: batches b%8==blockIdx%8 -> 2MB h working set per XCD L2.
__global__ __launch_bounds__(256, 6)
void kD(const float* __restrict__ h, const float* __restrict__ s_i,
        const float* __restrict__ s_j, const int* __restrict__ topk,
        const float* __restrict__ gnn_bias,
        float* __restrict__ outp, float* __restrict__ acc){
  __shared__ float sm[128];
  int t = threadIdx.x, wave = t >> 6, lane = t & 63;
  if (t < 128) sm[t] = 0.f;
  __syncthreads();
  int p = blockIdx.x;
  int xcd = p & 7, slot = p >> 3;
  int b = xcd + 8*(slot >> 6);               // 8 batches per XCD
  int chunk = slot & 63;                     // 16 rows per block
  const float* hb  = h   + (size_t)b * NN * DIM;
  const float* sjb = s_j + (size_t)b * NN;
  float gb = gnn_bias[lane];
  float psum = 0.f, psq = 0.f;
  #pragma unroll 1
  for (int it = 0; it < 4; it++){
    int nu = __builtin_amdgcn_readfirstlane(chunk*16 + wave*4 + it);
    float siv = s_i[(size_t)b*NN + nu];
    int idx[KK];
    #pragma unroll
    for (int k = 0; k < KK; k++)
      idx[k] = __builtin_amdgcn_readfirstlane(topk[nu*KK + k]);
    float g[KK];
    #pragma unroll
    for (int k = 0; k < KK; k++) g[k] = hb[idx[k]*DIM + lane];
    float xv[KK];
    #pragma unroll
    for (int k = 0; k < KK; k++){
      float x = siv + sjb[idx[k]];
      xv[k] = (x > 0.f) ? x : SLOPE * x;
    }
    float m = xv[0];
    #pragma unroll
    for (int k = 1; k < KK; k++) m = fmaxf(m, xv[k]);
    float ssum = 0.f;
    #pragma unroll
    for (int k = 0; k < KK; k++){ xv[k] = __expf(xv[k] - m); ssum += xv[k]; }
    float rinv = 1.f / ssum;
    float o = 0.f;
    #pragma unroll
    for (int k = 0; k < KK; k++) o += (xv[k]*rinv) * g[k];
    o += gb;
    outp[((size_t)b*NN + nu)*DIM + lane] = o;
    psum += o; psq += o*o;
  }
  atomicAdd(&sm[lane], psum);
  atomicAdd(&sm[64+lane], psq);
  __syncthreads();
  float* accr = acc + (p & (REPS-1))*128;
  if (t < 128) atomicAdd(&accr[t], sm[t]);
}

// ---------------- kE: reduce replicas + BN finalize -> prm ---------------
__global__ void kE(const float* __restrict__ acc, const float* __restrict__ gamma,
                   const float* __restrict__ beta, float* __restrict__ prm){
  int d = threadIdx.x;
  float smv = 0.f, sqv = 0.f;
  #pragma unroll
  for (int rp = 0; rp < REPS; rp++){
    smv += acc[rp*128 + d];
    sqv += acc[rp*128 + 64 + d];
  }
  float mean = smv * (1.f / BN_COUNT);
  float var  = sqv * (1.f / BN_COUNT) - mean*mean;
  float sc = gamma[d] * rsqrtf(var + EPSV);
  prm[d]    = sc;
  prm[64+d] = beta[d] - mean*sc;
}

// ------- kF: BN1 apply + relu + *emb -> rep ; BN2 stats ------------------
__global__ void kF(const float* __restrict__ outp, const float* __restrict__ emb,
                   const float* __restrict__ prm, float* __restrict__ rep,
                   float* __restrict__ acc2){
  __shared__ float chs[DIM], chq[DIM];
  int t = threadIdx.x;
  if (t < DIM){ chs[t] = 0.f; chq[t] = 0.f; }
  __syncthreads();
  int cbase = (t*4) & 63;
  float4 sc = *(const float4*)(prm + cbase);
  float4 bs = *(const float4*)(prm + 64 + cbase);
  float s0=0,s1=0,s2=0,s3=0,q0=0,q1=0,q2=0,q3=0;
  const float4* op4 = (const float4*)outp;
  const float4* em4 = (const float4*)emb;
  float4* rp4 = (float4*)rep;
  const int total = BB*NN*DIM/4;
  for (int e = blockIdx.x*256 + t; e < total; e += 2048*256){
    float4 x = op4[e];
    float4 em = em4[e & (NN*DIM/4 - 1)];
    float4 y;
    y.x = fmaxf(x.x*sc.x + bs.x, 0.f) * em.x;
    y.y = fmaxf(x.y*sc.y + bs.y, 0.f) * em.y;
    y.z = fmaxf(x.z*sc.z + bs.z, 0.f) * em.z;
    y.w = fmaxf(x.w*sc.w + bs.w, 0.f) * em.w;
    rp4[e] = y;
    s0 += y.x; q0 += y.x*y.x;
    s1 += y.y; q1 += y.y*y.y;
    s2 += y.z; q2 += y.z*y.z;
    s3 += y.w; q3 += y.w*y.w;
  }
  atomicAdd(&chs[cbase+0], s0); atomicAdd(&chq[cbase+0], q0);
  atomicAdd(&chs[cbase+1], s1); atomicAdd(&chq[cbase+1], q1);
  atomicAdd(&chs[cbase+2], s2); atomicAdd(&chq[cbase+2], q2);
  atomicAdd(&chs[cbase+3], s3); atomicAdd(&chq[cbase+3], q3);
  __syncthreads();
  float* acc2r = acc2 + (blockIdx.x & (REPS-1))*128;
  if (t < 128) atomicAdd(&acc2r[t], (t < 64) ? chs[t] : chq[t-64]);
}

// ------- kH: BN2 apply + relu + dot(out_w) -> fore -----------------------
__global__ void kH(const float* __restrict__ rep, const float* __restrict__ prm2,
                   const float* __restrict__ out_w, const float* __restrict__ out_b,
                   float* __restrict__ out){
  int t = threadIdx.x, wave = t >> 6, lane = t & 63;
  int c16 = lane & 15, rsub = lane >> 4;
  int cb = c16*4;
  float4 sc = *(const float4*)(prm2 + cb);
  float4 bs = *(const float4*)(prm2 + 64 + cb);
  float4 w4 = *(const float4*)(out_w + cb);
  float ob = out_b[0];
  int rbase = blockIdx.x*64 + wave*16;
  for (int i = 0; i < 16; i += 4){
    int r = rbase + i + rsub;
    float4 x = *(const float4*)(rep + (size_t)r*DIM + cb);
    float p = fmaxf(x.x*sc.x + bs.x, 0.f) * w4.x
            + fmaxf(x.y*sc.y + bs.y, 0.f) * w4.y
            + fmaxf(x.z*sc.z + bs.z, 0.f) * w4.z
            + fmaxf(x.w*sc.w + bs.w, 0.f) * w4.w;
    p += __shfl_xor(p, 1, 64); p += __shfl_xor(p, 2, 64);
    p += __shfl_xor(p, 4, 64); p += __shfl_xor(p, 8, 64);
    if (c16 == 0) out[r] = p + ob;
  }
}

extern "C" void kernel_launch(void* const* d_in, const int* in_sizes, int n_in,
                              void* d_out, int out_size, void* d_ws, size_t ws_size,
                              hipStream_t stream) {
  const float* data     = (const float*)d_in[0];
  const float* emb      = (const float*)d_in[2];
  const float* lin_w    = (const float*)d_in[3];
  const float* att_i    = (const float*)d_in[4];
  const float* att_j    = (const float*)d_in[5];
  const float* att_em_i = (const float*)d_in[6];
  const float* att_em_j = (const float*)d_in[7];
  const float* gnn_bias = (const float*)d_in[8];
  const float* bn1_g    = (const float*)d_in[9];
  const float* bn1_b    = (const float*)d_in[10];
  const float* bn2_g    = (const float*)d_in[11];
  const float* bn2_b    = (const float*)d_in[12];
  const float* out_w    = (const float*)d_in[13];
  const float* out_b    = (const float*)d_in[14];
  float* out = (float*)d_out;

  float* ws   = (float*)d_ws;
  float* h    = ws;                        // 4194304 floats (rep aliases)
  float* outp = ws + 4194304;              // 4194304
  float* s_i  = ws + 8388608;              // 65536
  float* s_j  = s_i + 65536;               // 65536
  int*   topk = (int*)(s_j + 65536);       // 20480 ints
  float* acc1 = (float*)(topk + NN*KK);    // REPS*128
  float* acc2 = acc1 + REPS*128;           // REPS*128
  float* prm1 = acc2 + REPS*128;           // 128
  float* prm2 = prm1 + 128;                // 128
  float* rep  = h;                         // h dead after kD

  kB<<<NN, 256, 0, stream>>>(emb, topk, acc1);
  kC<<<(BB*NN)/16, 256, 0, stream>>>(data, lin_w, att_i, att_j, att_em_i, att_em_j,
                                     emb, h, s_i, s_j);
  kD<<<(BB*NN)/16, 256, 0, stream>>>(h, s_i, s_j, topk, gnn_bias, outp, acc1);
  kE<<<1, 64, 0, stream>>>(acc1, bn1_g, bn1_b, prm1);
  kF<<<2048, 256, 0, stream>>>(outp, emb, prm1, rep, acc2);
  kE<<<1, 64, 0, stream>>>(acc2, bn2_g, bn2_b, prm2);
  kH<<<NN, 256, 0, stream>>>(rep, prm2, out_w, out_b, out);
}

// Round 7
// 202.592 us; speedup vs baseline: 1.9557x; 1.0736x over previous
//
#include <hip/hip_runtime.h>
#include <math.h>

#define BB   64
#define NN   1024
#define FIN  16
#define DIM  64
#define KK   20
#define EPSV 1e-5f
#define SLOPE 0.2f
#define BN_COUNT (BB*NN)
#define REPS 16

__device__ inline float wred_sum(float v){
  #pragma unroll
  for (int m = 32; m > 0; m >>= 1) v += __shfl_xor(v, m, 64);
  return v;
}

// ---------------- kG: keys[i][j] = dot(e_i,e_j)*rsqrt(|e_j|^2) -----------
// 64x64 tile GEMM, B-tile transposed in LDS (stride 68 kills bank conflicts).
// Per-row-i positive scale (1/|e_i|) omitted: irrelevant for per-row top-k.
// Block (0,0) also zeroes the BN accumulators.
__global__ void kG(const float* __restrict__ emb, float* __restrict__ keys,
                   float* __restrict__ accz){
  __shared__ float a_lds[64*68];
  __shared__ float bT[64*68];
  __shared__ float rs[64];
  int t = threadIdx.x;
  int it = blockIdx.x, jt = blockIdx.y;
  if (it == 0 && jt == 0){
    for (int u = t; u < 2*REPS*128; u += 256) accz[u] = 0.f;
  }
  const float4* e4 = (const float4*)emb;
  #pragma unroll
  for (int u0 = 0; u0 < 1024; u0 += 256){
    int u = u0 + t;
    int r = u >> 4, q = u & 15;
    float4 v = e4[(it*64 + r)*16 + q];
    *(float4*)&a_lds[r*68 + q*4] = v;
  }
  #pragma unroll
  for (int u0 = 0; u0 < 1024; u0 += 256){
    int u = u0 + t;
    int r = u >> 4, q = u & 15;
    float4 v = e4[(jt*64 + r)*16 + q];
    int d0 = q*4;
    bT[(d0+0)*68 + r] = v.x;
    bT[(d0+1)*68 + r] = v.y;
    bT[(d0+2)*68 + r] = v.z;
    bT[(d0+3)*68 + r] = v.w;
  }
  __syncthreads();
  if (t < 64){
    float s = 0.f;
    #pragma unroll
    for (int d = 0; d < 64; d++){ float x = bT[d*68 + t]; s += x*x; }
    rs[t] = rsqrtf(s);
  }
  __syncthreads();
  int tx = t & 15, ty = t >> 4;
  float4 acc[4];
  #pragma unroll
  for (int r = 0; r < 4; r++) acc[r] = (float4){0.f,0.f,0.f,0.f};
  #pragma unroll
  for (int d4 = 0; d4 < 16; d4++){
    float4 av[4], bv[4];
    #pragma unroll
    for (int r = 0; r < 4; r++) av[r] = *(const float4*)&a_lds[(ty*4+r)*68 + d4*4];
    #pragma unroll
    for (int dd = 0; dd < 4; dd++) bv[dd] = *(const float4*)&bT[(d4*4+dd)*68 + tx*4];
    #pragma unroll
    for (int r = 0; r < 4; r++){
      acc[r].x += av[r].x*bv[0].x; acc[r].y += av[r].x*bv[0].y;
      acc[r].z += av[r].x*bv[0].z; acc[r].w += av[r].x*bv[0].w;
      acc[r].x += av[r].y*bv[1].x; acc[r].y += av[r].y*bv[1].y;
      acc[r].z += av[r].y*bv[1].z; acc[r].w += av[r].y*bv[1].w;
      acc[r].x += av[r].z*bv[2].x; acc[r].y += av[r].z*bv[2].y;
      acc[r].z += av[r].z*bv[2].z; acc[r].w += av[r].z*bv[2].w;
      acc[r].x += av[r].w*bv[3].x; acc[r].y += av[r].w*bv[3].y;
      acc[r].z += av[r].w*bv[3].z; acc[r].w += av[r].w*bv[3].w;
    }
  }
  float4 rs4 = {rs[tx*4+0], rs[tx*4+1], rs[tx*4+2], rs[tx*4+3]};
  float4* k4 = (float4*)keys;
  #pragma unroll
  for (int r = 0; r < 4; r++){
    int gi = it*64 + ty*4 + r;
    float4 o = {acc[r].x*rs4.x, acc[r].y*rs4.y, acc[r].z*rs4.z, acc[r].w*rs4.w};
    k4[gi*256 + jt*16 + tx] = o;
  }
}

// ---------------- kS: top-20 per row (lax.top_k semantics) ---------------
// One wave per 2 rows (interleaved for ILP). Keys register-resident
// (16/lane); cached local max — only the winner lane rescans its 16.
// Element m of lane: j = (m>>2)*256 + lane*4 + (m&3)  (monotone in m).
__global__ void kS(const float* __restrict__ keys, int* __restrict__ topk){
  int t = threadIdx.x, wave = t >> 6, lane = t & 63;
  int i0 = blockIdx.x*4 + wave*2;
  const float4* k4 = (const float4*)keys;
  float cA[16], cB[16];
  #pragma unroll
  for (int q = 0; q < 4; q++){
    float4 vA = k4[(i0+0)*256 + q*64 + lane];
    float4 vB = k4[(i0+1)*256 + q*64 + lane];
    cA[q*4+0]=vA.x; cA[q*4+1]=vA.y; cA[q*4+2]=vA.z; cA[q*4+3]=vA.w;
    cB[q*4+0]=vB.x; cB[q*4+1]=vB.y; cB[q*4+2]=vB.z; cB[q*4+3]=vB.w;
  }
  float lvA = cA[0]; int liA = 0;
  float lvB = cB[0]; int liB = 0;
  #pragma unroll
  for (int m = 1; m < 16; m++){
    if (cA[m] > lvA){ lvA = cA[m]; liA = m; }
    if (cB[m] > lvB){ lvB = cB[m]; liB = m; }
  }
  #pragma unroll 1
  for (int k = 0; k < KK; k++){
    float bvA = lvA; int bjA = ((liA>>2)<<8) + (lane<<2) + (liA&3);
    float bvB = lvB; int bjB = ((liB>>2)<<8) + (lane<<2) + (liB&3);
    #pragma unroll
    for (int msk = 32; msk > 0; msk >>= 1){
      float pvA = __shfl_xor(bvA, msk, 64); int pjA = __shfl_xor(bjA, msk, 64);
      float pvB = __shfl_xor(bvB, msk, 64); int pjB = __shfl_xor(bjB, msk, 64);
      if (pvA > bvA || (pvA == bvA && pjA < bjA)){ bvA = pvA; bjA = pjA; }
      if (pvB > bvB || (pvB == bvB && pjB < bjB)){ bvB = pvB; bjB = pjB; }
    }
    if (lane == 0){
      topk[(i0+0)*KK + k] = bjA;
      topk[(i0+1)*KK + k] = bjB;
    }
    if (((bjA>>2)&63) == lane){
      cA[((bjA>>8)<<2) + (bjA&3)] = -1e30f;
      lvA = cA[0]; liA = 0;
      #pragma unroll
      for (int m = 1; m < 16; m++) if (cA[m] > lvA){ lvA = cA[m]; liA = m; }
    }
    if (((bjB>>2)&63) == lane){
      cB[((bjB>>8)<<2) + (bjB&3)] = -1e30f;
      lvB = cB[0]; liB = 0;
      #pragma unroll
      for (int m = 1; m < 16; m++) if (cB[m] > lvB){ lvB = cB[m]; liB = m; }
    }
  }
}

// ---------------- kC: h = data @ lin_w^T ; s_i, s_j (incl. emb terms) ----
__global__ void kC(const float* __restrict__ data, const float* __restrict__ lin_w,
                   const float* __restrict__ att_i, const float* __restrict__ att_j,
                   const float* __restrict__ att_em_i, const float* __restrict__ att_em_j,
                   const float* __restrict__ emb,
                   float* __restrict__ h, float* __restrict__ s_i, float* __restrict__ s_j){
  __shared__ float lw[FIN*DIM];              // lw[f*64+d]
  __shared__ __align__(16) float sd[16][FIN];
  int t = threadIdx.x;
  for (int u = t; u < FIN*DIM; u += 256){
    int d = u >> 4, f = u & 15;
    lw[f*DIM + d] = lin_w[u];
  }
  int r0 = blockIdx.x*16;
  sd[t >> 4][t & 15] = data[r0*FIN + t];
  __syncthreads();
  int wave = t >> 6, lane = t & 63;
  float ai = att_i[lane], aj = att_j[lane];
  float aemi = att_em_i[lane], aemj = att_em_j[lane];
  #pragma unroll
  for (int q = 0; q < 4; q++){
    int row = wave*4 + q;
    int r = r0 + row;
    int n = r & (NN-1);
    float acc = 0.f;
    #pragma unroll
    for (int f4 = 0; f4 < 4; f4++){
      float4 d4 = ((const float4*)sd[row])[f4];
      acc += d4.x * lw[(f4*4+0)*DIM + lane];
      acc += d4.y * lw[(f4*4+1)*DIM + lane];
      acc += d4.z * lw[(f4*4+2)*DIM + lane];
      acc += d4.w * lw[(f4*4+3)*DIM + lane];
    }
    h[r*DIM + lane] = acc;
    float ev = emb[n*DIM + lane];
    float si = wred_sum(acc*ai + ev*aemi);
    float sj = wred_sum(acc*aj + ev*aemj);
    if (lane == 0){ s_i[r] = si; s_j[r] = sj; }
  }
}

// ------- kD: wave-per-row softmax-K + gather + BN1 stats -----------------
__global__ __launch_bounds__(256, 6)
void kD(const float* __restrict__ h, const float* __restrict__ s_i,
        const float* __restrict__ s_j, const int* __restrict__ topk,
        const float* __restrict__ gnn_bias,
        float* __restrict__ outp, float* __restrict__ acc){
  __shared__ float sm[128];
  int t = threadIdx.x, wave = t >> 6, lane = t & 63;
  if (t < 128) sm[t] = 0.f;
  __syncthreads();
  int p = blockIdx.x;
  int xcd = p & 7, slot = p >> 3;
  int b = xcd + 8*(slot >> 6);               // 8 batches per XCD
  int chunk = slot & 63;                     // 16 rows per block
  const float* hb  = h   + (size_t)b * NN * DIM;
  const float* sjb = s_j + (size_t)b * NN;
  float gb = gnn_bias[lane];
  float psum = 0.f, psq = 0.f;
  #pragma unroll 1
  for (int it = 0; it < 4; it++){
    int nu = __builtin_amdgcn_readfirstlane(chunk*16 + wave*4 + it);
    float siv = s_i[(size_t)b*NN + nu];
    int idx[KK];
    #pragma unroll
    for (int k = 0; k < KK; k++)
      idx[k] = __builtin_amdgcn_readfirstlane(topk[nu*KK + k]);
    float g[KK];
    #pragma unroll
    for (int k = 0; k < KK; k++) g[k] = hb[idx[k]*DIM + lane];
    float xv[KK];
    #pragma unroll
    for (int k = 0; k < KK; k++){
      float x = siv + sjb[idx[k]];
      xv[k] = (x > 0.f) ? x : SLOPE * x;
    }
    float m = xv[0];
    #pragma unroll
    for (int k = 1; k < KK; k++) m = fmaxf(m, xv[k]);
    float ssum = 0.f;
    #pragma unroll
    for (int k = 0; k < KK; k++){ xv[k] = __expf(xv[k] - m); ssum += xv[k]; }
    float rinv = 1.f / ssum;
    float o = 0.f;
    #pragma unroll
    for (int k = 0; k < KK; k++) o += (xv[k]*rinv) * g[k];
    o += gb;
    outp[((size_t)b*NN + nu)*DIM + lane] = o;
    psum += o; psq += o*o;
  }
  atomicAdd(&sm[lane], psum);
  atomicAdd(&sm[64+lane], psq);
  __syncthreads();
  float* accr = acc + (p & (REPS-1))*128;
  if (t < 128) atomicAdd(&accr[t], sm[t]);
}

// ------- kF: BN1 finalize (in-block) + apply + relu + *emb ; BN2 stats ---
__global__ void kF(const float* __restrict__ outp, const float* __restrict__ emb,
                   const float* __restrict__ acc, const float* __restrict__ bn1_g,
                   const float* __restrict__ bn1_b, float* __restrict__ rep,
                   float* __restrict__ acc2){
  __shared__ float prm[128];
  __shared__ float chs[DIM], chq[DIM];
  int t = threadIdx.x;
  if (t < DIM){ chs[t] = 0.f; chq[t] = 0.f; }
  if (t < 64){
    float smv = 0.f, sqv = 0.f;
    #pragma unroll
    for (int rp = 0; rp < REPS; rp++){
      smv += acc[rp*128 + t];
      sqv += acc[rp*128 + 64 + t];
    }
    float mean = smv * (1.f / BN_COUNT);
    float var  = sqv * (1.f / BN_COUNT) - mean*mean;
    float sc = bn1_g[t] * rsqrtf(var + EPSV);
    prm[t]    = sc;
    prm[64+t] = bn1_b[t] - mean*sc;
  }
  __syncthreads();
  int cbase = (t*4) & 63;
  float4 sc = *(const float4*)(prm + cbase);
  float4 bs = *(const float4*)(prm + 64 + cbase);
  float s0=0,s1=0,s2=0,s3=0,q0=0,q1=0,q2=0,q3=0;
  const float4* op4 = (const float4*)outp;
  const float4* em4 = (const float4*)emb;
  float4* rp4 = (float4*)rep;
  const int total = BB*NN*DIM/4;
  for (int e = blockIdx.x*256 + t; e < total; e += 2048*256){
    float4 x = op4[e];
    float4 em = em4[e & (NN*DIM/4 - 1)];
    float4 y;
    y.x = fmaxf(x.x*sc.x + bs.x, 0.f) * em.x;
    y.y = fmaxf(x.y*sc.y + bs.y, 0.f) * em.y;
    y.z = fmaxf(x.z*sc.z + bs.z, 0.f) * em.z;
    y.w = fmaxf(x.w*sc.w + bs.w, 0.f) * em.w;
    rp4[e] = y;
    s0 += y.x; q0 += y.x*y.x;
    s1 += y.y; q1 += y.y*y.y;
    s2 += y.z; q2 += y.z*y.z;
    s3 += y.w; q3 += y.w*y.w;
  }
  atomicAdd(&chs[cbase+0], s0); atomicAdd(&chq[cbase+0], q0);
  atomicAdd(&chs[cbase+1], s1); atomicAdd(&chq[cbase+1], q1);
  atomicAdd(&chs[cbase+2], s2); atomicAdd(&chq[cbase+2], q2);
  atomicAdd(&chs[cbase+3], s3); atomicAdd(&chq[cbase+3], q3);
  __syncthreads();
  float* acc2r = acc2 + (blockIdx.x & (REPS-1))*128;
  if (t < 128) atomicAdd(&acc2r[t], (t < 64) ? chs[t] : chq[t-64]);
}

// ------- kH: BN2 finalize (in-block) + apply + relu + dot(out_w) ---------
__global__ void kH(const float* __restrict__ rep, const float* __restrict__ acc2,
                   const float* __restrict__ bn2_g, const float* __restrict__ bn2_b,
                   const float* __restrict__ out_w, const float* __restrict__ out_b,
                   float* __restrict__ out){
  __shared__ float prm[128];
  int t = threadIdx.x, wave = t >> 6, lane = t & 63;
  if (t < 64){
    float smv = 0.f, sqv = 0.f;
    #pragma unroll
    for (int rp = 0; rp < REPS; rp++){
      smv += acc2[rp*128 + t];
      sqv += acc2[rp*128 + 64 + t];
    }
    float mean = smv * (1.f / BN_COUNT);
    float var  = sqv * (1.f / BN_COUNT) - mean*mean;
    float sc = bn2_g[t] * rsqrtf(var + EPSV);
    prm[t]    = sc;
    prm[64+t] = bn2_b[t] - mean*sc;
  }
  __syncthreads();
  int c16 = lane & 15, rsub = lane >> 4;
  int cb = c16*4;
  float4 sc = *(const float4*)(prm + cb);
  float4 bs = *(const float4*)(prm + 64 + cb);
  float4 w4 = *(const float4*)(out_w + cb);
  float ob = out_b[0];
  int rbase = blockIdx.x*64 + wave*16;
  for (int i = 0; i < 16; i += 4){
    int r = rbase + i + rsub;
    float4 x = *(const float4*)(rep + (size_t)r*DIM + cb);
    float p = fmaxf(x.x*sc.x + bs.x, 0.f) * w4.x
            + fmaxf(x.y*sc.y + bs.y, 0.f) * w4.y
            + fmaxf(x.z*sc.z + bs.z, 0.f) * w4.z
            + fmaxf(x.w*sc.w + bs.w, 0.f) * w4.w;
    p += __shfl_xor(p, 1, 64); p += __shfl_xor(p, 2, 64);
    p += __shfl_xor(p, 4, 64); p += __shfl_xor(p, 8, 64);
    if (c16 == 0) out[r] = p + ob;
  }
}

extern "C" void kernel_launch(void* const* d_in, const int* in_sizes, int n_in,
                              void* d_out, int out_size, void* d_ws, size_t ws_size,
                              hipStream_t stream) {
  const float* data     = (const float*)d_in[0];
  const float* emb      = (const float*)d_in[2];
  const float* lin_w    = (const float*)d_in[3];
  const float* att_i    = (const float*)d_in[4];
  const float* att_j    = (const float*)d_in[5];
  const float* att_em_i = (const float*)d_in[6];
  const float* att_em_j = (const float*)d_in[7];
  const float* gnn_bias = (const float*)d_in[8];
  const float* bn1_g    = (const float*)d_in[9];
  const float* bn1_b    = (const float*)d_in[10];
  const float* bn2_g    = (const float*)d_in[11];
  const float* bn2_b    = (const float*)d_in[12];
  const float* out_w    = (const float*)d_in[13];
  const float* out_b    = (const float*)d_in[14];
  float* out = (float*)d_out;

  float* ws   = (float*)d_ws;
  float* h    = ws;                        // 4194304 floats (rep aliases)
  float* outp = ws + 4194304;              // 4194304 (keys aliases first 1M)
  float* s_i  = ws + 8388608;              // 65536
  float* s_j  = s_i + 65536;               // 65536
  int*   topk = (int*)(s_j + 65536);       // 20480 ints
  float* acc1 = (float*)(topk + NN*KK);    // REPS*128
  float* acc2 = acc1 + REPS*128;           // REPS*128
  float* keys = outp;                      // 1M floats, dead before kD writes
  float* rep  = h;                         // h dead after kD

  kG<<<dim3(16,16), 256, 0, stream>>>(emb, keys, acc1);
  kS<<<256, 128, 0, stream>>>(keys, topk);
  kC<<<(BB*NN)/16, 256, 0, stream>>>(data, lin_w, att_i, att_j, att_em_i, att_em_j,
                                     emb, h, s_i, s_j);
  kD<<<(BB*NN)/16, 256, 0, stream>>>(h, s_i, s_j, topk, gnn_bias, outp, acc1);
  kF<<<2048, 256, 0, stream>>>(outp, emb, acc1, bn1_g, bn1_b, rep, acc2);
  kH<<<NN, 256, 0, stream>>>(rep, acc2, bn2_g, bn2_b, out_w, out_b, out);
}

// Round 8
// 197.560 us; speedup vs baseline: 2.0055x; 1.0255x over previous
//
#include <hip/hip_runtime.h>
#include <math.h>

#define BB   64
#define NN   1024
#define FIN  16
#define DIM  64
#define KK   20
#define EPSV 1e-5f
#define SLOPE 0.2f
#define BN_COUNT (BB*NN)
#define RD 32   // acc1 replicas (kD: 8192 blocks -> 256 chains/address)
#define RF 16   // acc2 replicas (kF: 2048 blocks -> 128 chains/address)

__device__ inline float wred_sum(float v){
  #pragma unroll
  for (int m = 32; m > 0; m >>= 1) v += __shfl_xor(v, m, 64);
  return v;
}

// ---------------- kGC: fused kG (blocks 0..255) + kC (blocks 256..4351) --
// kG: keys[i][j] = dot(e_i,e_j)*rsqrt(|e_j|^2)  (row-i scale irrelevant for
//     per-row top-k). 64x64 LDS-tiled GEMM, B transposed, stride 68.
// kC: h = data @ lin_w^T ; s_i/s_j = h·att + emb·att_em.
__global__ __launch_bounds__(256)
void kGC(const float* __restrict__ emb, const float* __restrict__ data,
         const float* __restrict__ lin_w,
         const float* __restrict__ att_i, const float* __restrict__ att_j,
         const float* __restrict__ att_em_i, const float* __restrict__ att_em_j,
         float* __restrict__ keys, float* __restrict__ h,
         float* __restrict__ s_i, float* __restrict__ s_j,
         float* __restrict__ accz){
  __shared__ float smem[64*68*2 + 64];
  int p = blockIdx.x, t = threadIdx.x;
  if (p == 0){
    for (int u = t; u < (RD+RF)*128; u += 256) accz[u] = 0.f;
  }
  if (p < 256){
    // ---------------- kG part ----------------
    float* a_lds = smem;
    float* bT    = smem + 64*68;
    float* rs    = smem + 2*64*68;
    int it = p >> 4, jt = p & 15;
    const float4* e4 = (const float4*)emb;
    #pragma unroll
    for (int u0 = 0; u0 < 1024; u0 += 256){
      int u = u0 + t;
      int r = u >> 4, q = u & 15;
      float4 v = e4[(it*64 + r)*16 + q];
      *(float4*)&a_lds[r*68 + q*4] = v;
    }
    #pragma unroll
    for (int u0 = 0; u0 < 1024; u0 += 256){
      int u = u0 + t;
      int r = u >> 4, q = u & 15;
      float4 v = e4[(jt*64 + r)*16 + q];
      int d0 = q*4;
      bT[(d0+0)*68 + r] = v.x;
      bT[(d0+1)*68 + r] = v.y;
      bT[(d0+2)*68 + r] = v.z;
      bT[(d0+3)*68 + r] = v.w;
    }
    __syncthreads();
    if (t < 64){
      float s = 0.f;
      #pragma unroll
      for (int d = 0; d < 64; d++){ float x = bT[d*68 + t]; s += x*x; }
      rs[t] = rsqrtf(s);
    }
    __syncthreads();
    int tx = t & 15, ty = t >> 4;
    float4 acc[4];
    #pragma unroll
    for (int r = 0; r < 4; r++) acc[r] = (float4){0.f,0.f,0.f,0.f};
    #pragma unroll
    for (int d4 = 0; d4 < 16; d4++){
      float4 av[4], bv[4];
      #pragma unroll
      for (int r = 0; r < 4; r++) av[r] = *(const float4*)&a_lds[(ty*4+r)*68 + d4*4];
      #pragma unroll
      for (int dd = 0; dd < 4; dd++) bv[dd] = *(const float4*)&bT[(d4*4+dd)*68 + tx*4];
      #pragma unroll
      for (int r = 0; r < 4; r++){
        acc[r].x += av[r].x*bv[0].x; acc[r].y += av[r].x*bv[0].y;
        acc[r].z += av[r].x*bv[0].z; acc[r].w += av[r].x*bv[0].w;
        acc[r].x += av[r].y*bv[1].x; acc[r].y += av[r].y*bv[1].y;
        acc[r].z += av[r].y*bv[1].z; acc[r].w += av[r].y*bv[1].w;
        acc[r].x += av[r].z*bv[2].x; acc[r].y += av[r].z*bv[2].y;
        acc[r].z += av[r].z*bv[2].z; acc[r].w += av[r].z*bv[2].w;
        acc[r].x += av[r].w*bv[3].x; acc[r].y += av[r].w*bv[3].y;
        acc[r].z += av[r].w*bv[3].z; acc[r].w += av[r].w*bv[3].w;
      }
    }
    float4 rs4 = {rs[tx*4+0], rs[tx*4+1], rs[tx*4+2], rs[tx*4+3]};
    float4* k4 = (float4*)keys;
    #pragma unroll
    for (int r = 0; r < 4; r++){
      int gi = it*64 + ty*4 + r;
      float4 o = {acc[r].x*rs4.x, acc[r].y*rs4.y, acc[r].z*rs4.z, acc[r].w*rs4.w};
      k4[gi*256 + jt*16 + tx] = o;
    }
  } else {
    // ---------------- kC part ----------------
    float* lw = smem;                 // [f*64+d]
    float* sd = smem + 1024;          // 16 rows x 16 f
    for (int u = t; u < FIN*DIM; u += 256){
      int d = u >> 4, f = u & 15;
      lw[f*DIM + d] = lin_w[u];
    }
    int r0 = (p - 256)*16;
    sd[t] = data[r0*FIN + t];
    __syncthreads();
    int wave = t >> 6, lane = t & 63;
    float ai = att_i[lane], aj = att_j[lane];
    float aemi = att_em_i[lane], aemj = att_em_j[lane];
    #pragma unroll
    for (int q = 0; q < 4; q++){
      int row = wave*4 + q;
      int r = r0 + row;
      int n = r & (NN-1);
      float acc = 0.f;
      #pragma unroll
      for (int f4 = 0; f4 < 4; f4++){
        float4 d4 = ((const float4*)(sd + row*FIN))[f4];
        acc += d4.x * lw[(f4*4+0)*DIM + lane];
        acc += d4.y * lw[(f4*4+1)*DIM + lane];
        acc += d4.z * lw[(f4*4+2)*DIM + lane];
        acc += d4.w * lw[(f4*4+3)*DIM + lane];
      }
      h[r*DIM + lane] = acc;
      float ev = emb[n*DIM + lane];
      float si = wred_sum(acc*ai + ev*aemi);
      float sj = wred_sum(acc*aj + ev*aemj);
      if (lane == 0){ s_i[r] = si; s_j[r] = sj; }
    }
  }
}

// ---------------- kS: top-20 per row (lax.top_k semantics) ---------------
__global__ void kS(const float* __restrict__ keys, int* __restrict__ topk){
  int t = threadIdx.x, wave = t >> 6, lane = t & 63;
  int i0 = blockIdx.x*4 + wave*2;
  const float4* k4 = (const float4*)keys;
  float cA[16], cB[16];
  #pragma unroll
  for (int q = 0; q < 4; q++){
    float4 vA = k4[(i0+0)*256 + q*64 + lane];
    float4 vB = k4[(i0+1)*256 + q*64 + lane];
    cA[q*4+0]=vA.x; cA[q*4+1]=vA.y; cA[q*4+2]=vA.z; cA[q*4+3]=vA.w;
    cB[q*4+0]=vB.x; cB[q*4+1]=vB.y; cB[q*4+2]=vB.z; cB[q*4+3]=vB.w;
  }
  float lvA = cA[0]; int liA = 0;
  float lvB = cB[0]; int liB = 0;
  #pragma unroll
  for (int m = 1; m < 16; m++){
    if (cA[m] > lvA){ lvA = cA[m]; liA = m; }
    if (cB[m] > lvB){ lvB = cB[m]; liB = m; }
  }
  #pragma unroll 1
  for (int k = 0; k < KK; k++){
    float bvA = lvA; int bjA = ((liA>>2)<<8) + (lane<<2) + (liA&3);
    float bvB = lvB; int bjB = ((liB>>2)<<8) + (lane<<2) + (liB&3);
    #pragma unroll
    for (int msk = 32; msk > 0; msk >>= 1){
      float pvA = __shfl_xor(bvA, msk, 64); int pjA = __shfl_xor(bjA, msk, 64);
      float pvB = __shfl_xor(bvB, msk, 64); int pjB = __shfl_xor(bjB, msk, 64);
      if (pvA > bvA || (pvA == bvA && pjA < bjA)){ bvA = pvA; bjA = pjA; }
      if (pvB > bvB || (pvB == bvB && pjB < bjB)){ bvB = pvB; bjB = pjB; }
    }
    if (lane == 0){
      topk[(i0+0)*KK + k] = bjA;
      topk[(i0+1)*KK + k] = bjB;
    }
    if (((bjA>>2)&63) == lane){
      cA[((bjA>>8)<<2) + (bjA&3)] = -1e30f;
      lvA = cA[0]; liA = 0;
      #pragma unroll
      for (int m = 1; m < 16; m++) if (cA[m] > lvA){ lvA = cA[m]; liA = m; }
    }
    if (((bjB>>2)&63) == lane){
      cB[((bjB>>8)<<2) + (bjB&3)] = -1e30f;
      lvB = cB[0]; liB = 0;
      #pragma unroll
      for (int m = 1; m < 16; m++) if (cB[m] > lvB){ lvB = cB[m]; liB = m; }
    }
  }
}

// ------- kD: wave-per-row softmax-K + gather + BN1 stats -----------------
// 2 rows/wave fully unrolled: row1's scalar topk loads (lgkm) and gathers
// (vm) overlap row0's. XCD-swizzled: b%8==blockIdx%8 -> 2MB L2 set/XCD.
__global__ __launch_bounds__(256, 4)
void kD(const float* __restrict__ h, const float* __restrict__ s_i,
        const float* __restrict__ s_j, const int* __restrict__ topk,
        const float* __restrict__ gnn_bias,
        float* __restrict__ outp, float* __restrict__ acc){
  __shared__ float sm[128];
  int t = threadIdx.x, wave = t >> 6, lane = t & 63;
  if (t < 128) sm[t] = 0.f;
  __syncthreads();
  int p = blockIdx.x;                        // 8192 blocks, 8 rows each
  int xcd = p & 7, slot = p >> 3;            // 1024 slots
  int b = xcd + 8*(slot >> 7);               // 8 batches per XCD
  int chunk = slot & 127;                    // 128 chunks x 8 rows
  const float* hb  = h   + (size_t)b * NN * DIM;
  const float* sjb = s_j + (size_t)b * NN;
  float gb = gnn_bias[lane];
  float psum = 0.f, psq = 0.f;
  #pragma unroll
  for (int it = 0; it < 2; it++){
    int nu = __builtin_amdgcn_readfirstlane(chunk*8 + wave*2 + it);
    float siv = s_i[(size_t)b*NN + nu];
    int idx[KK];
    #pragma unroll
    for (int k = 0; k < KK; k++)
      idx[k] = __builtin_amdgcn_readfirstlane(topk[nu*KK + k]);
    float g[KK];
    #pragma unroll
    for (int k = 0; k < KK; k++) g[k] = hb[idx[k]*DIM + lane];
    float xv[KK];
    #pragma unroll
    for (int k = 0; k < KK; k++){
      float x = siv + sjb[idx[k]];
      xv[k] = (x > 0.f) ? x : SLOPE * x;
    }
    float m = xv[0];
    #pragma unroll
    for (int k = 1; k < KK; k++) m = fmaxf(m, xv[k]);
    float ssum = 0.f;
    #pragma unroll
    for (int k = 0; k < KK; k++){ xv[k] = __expf(xv[k] - m); ssum += xv[k]; }
    float rinv = 1.f / ssum;
    float o = 0.f;
    #pragma unroll
    for (int k = 0; k < KK; k++) o += (xv[k]*rinv) * g[k];
    o += gb;
    outp[((size_t)b*NN + nu)*DIM + lane] = o;
    psum += o; psq += o*o;
  }
  atomicAdd(&sm[lane], psum);
  atomicAdd(&sm[64+lane], psq);
  __syncthreads();
  float* accr = acc + (p & (RD-1))*128;
  if (t < 128) atomicAdd(&accr[t], sm[t]);
}

// ------- kF: BN1 finalize (in-block) + BN2 stats over relu(bn1)*emb ------
// Stats-only: rep is never materialized (kH recomputes it inline).
__global__ void kF(const float* __restrict__ outp, const float* __restrict__ emb,
                   const float* __restrict__ acc, const float* __restrict__ bn1_g,
                   const float* __restrict__ bn1_b, float* __restrict__ acc2){
  __shared__ float prm[128];
  __shared__ float chs[DIM], chq[DIM];
  int t = threadIdx.x;
  if (t < DIM){ chs[t] = 0.f; chq[t] = 0.f; }
  if (t < 64){
    float smv = 0.f, sqv = 0.f;
    #pragma unroll
    for (int rp = 0; rp < RD; rp++){
      smv += acc[rp*128 + t];
      sqv += acc[rp*128 + 64 + t];
    }
    float mean = smv * (1.f / BN_COUNT);
    float var  = sqv * (1.f / BN_COUNT) - mean*mean;
    float sc = bn1_g[t] * rsqrtf(var + EPSV);
    prm[t]    = sc;
    prm[64+t] = bn1_b[t] - mean*sc;
  }
  __syncthreads();
  int cbase = (t*4) & 63;
  float4 sc = *(const float4*)(prm + cbase);
  float4 bs = *(const float4*)(prm + 64 + cbase);
  float s0=0,s1=0,s2=0,s3=0,q0=0,q1=0,q2=0,q3=0;
  const float4* op4 = (const float4*)outp;
  const float4* em4 = (const float4*)emb;
  const int total = BB*NN*DIM/4;
  for (int e = blockIdx.x*256 + t; e < total; e += 2048*256){
    float4 x = op4[e];
    float4 em = em4[e & (NN*DIM/4 - 1)];
    float4 y;
    y.x = fmaxf(x.x*sc.x + bs.x, 0.f) * em.x;
    y.y = fmaxf(x.y*sc.y + bs.y, 0.f) * em.y;
    y.z = fmaxf(x.z*sc.z + bs.z, 0.f) * em.z;
    y.w = fmaxf(x.w*sc.w + bs.w, 0.f) * em.w;
    s0 += y.x; q0 += y.x*y.x;
    s1 += y.y; q1 += y.y*y.y;
    s2 += y.z; q2 += y.z*y.z;
    s3 += y.w; q3 += y.w*y.w;
  }
  atomicAdd(&chs[cbase+0], s0); atomicAdd(&chq[cbase+0], q0);
  atomicAdd(&chs[cbase+1], s1); atomicAdd(&chq[cbase+1], q1);
  atomicAdd(&chs[cbase+2], s2); atomicAdd(&chq[cbase+2], q2);
  atomicAdd(&chs[cbase+3], s3); atomicAdd(&chq[cbase+3], q3);
  __syncthreads();
  float* acc2r = acc2 + (blockIdx.x & (RF-1))*128;
  if (t < 128) atomicAdd(&acc2r[t], (t < 64) ? chs[t] : chq[t-64]);
}

// ------- kH: finalize BN1+BN2 (in-block), recompute rep inline, dot ------
__global__ void kH(const float* __restrict__ outp, const float* __restrict__ emb,
                   const float* __restrict__ acc, const float* __restrict__ acc2,
                   const float* __restrict__ bn1_g, const float* __restrict__ bn1_b,
                   const float* __restrict__ bn2_g, const float* __restrict__ bn2_b,
                   const float* __restrict__ out_w, const float* __restrict__ out_b,
                   float* __restrict__ out){
  __shared__ float prm[256];   // [0:128) bn1 sc/bias, [128:256) bn2 sc/bias
  int t = threadIdx.x, wave = t >> 6, lane = t & 63;
  if (t < 64){
    float smv = 0.f, sqv = 0.f;
    #pragma unroll
    for (int rp = 0; rp < RD; rp++){
      smv += acc[rp*128 + t];
      sqv += acc[rp*128 + 64 + t];
    }
    float mean = smv * (1.f / BN_COUNT);
    float var  = sqv * (1.f / BN_COUNT) - mean*mean;
    float sc = bn1_g[t] * rsqrtf(var + EPSV);
    prm[t]    = sc;
    prm[64+t] = bn1_b[t] - mean*sc;
  } else if (t < 128) {
    int d = t - 64;
    float smv = 0.f, sqv = 0.f;
    #pragma unroll
    for (int rp = 0; rp < RF; rp++){
      smv += acc2[rp*128 + d];
      sqv += acc2[rp*128 + 64 + d];
    }
    float mean = smv * (1.f / BN_COUNT);
    float var  = sqv * (1.f / BN_COUNT) - mean*mean;
    float sc = bn2_g[d] * rsqrtf(var + EPSV);
    prm[128+d] = sc;
    prm[192+d] = bn2_b[d] - mean*sc;
  }
  __syncthreads();
  int c16 = lane & 15, rsub = lane >> 4;
  int cb = c16*4;
  float4 sc1 = *(const float4*)(prm + cb);
  float4 bs1 = *(const float4*)(prm + 64 + cb);
  float4 sc2 = *(const float4*)(prm + 128 + cb);
  float4 bs2 = *(const float4*)(prm + 192 + cb);
  float4 w4 = *(const float4*)(out_w + cb);
  float ob = out_b[0];
  int rbase = blockIdx.x*64 + wave*16;
  #pragma unroll 1
  for (int i = 0; i < 16; i += 4){
    int r = rbase + i + rsub;
    int n = r & (NN-1);
    float4 x  = *(const float4*)(outp + (size_t)r*DIM + cb);
    float4 em = *(const float4*)(emb + n*DIM + cb);
    float4 y;
    y.x = fmaxf(x.x*sc1.x + bs1.x, 0.f) * em.x;
    y.y = fmaxf(x.y*sc1.y + bs1.y, 0.f) * em.y;
    y.z = fmaxf(x.z*sc1.z + bs1.z, 0.f) * em.z;
    y.w = fmaxf(x.w*sc1.w + bs1.w, 0.f) * em.w;
    float p = fmaxf(y.x*sc2.x + bs2.x, 0.f) * w4.x
            + fmaxf(y.y*sc2.y + bs2.y, 0.f) * w4.y
            + fmaxf(y.z*sc2.z + bs2.z, 0.f) * w4.z
            + fmaxf(y.w*sc2.w + bs2.w, 0.f) * w4.w;
    p += __shfl_xor(p, 1, 64); p += __shfl_xor(p, 2, 64);
    p += __shfl_xor(p, 4, 64); p += __shfl_xor(p, 8, 64);
    if (c16 == 0) out[r] = p + ob;
  }
}

extern "C" void kernel_launch(void* const* d_in, const int* in_sizes, int n_in,
                              void* d_out, int out_size, void* d_ws, size_t ws_size,
                              hipStream_t stream) {
  const float* data     = (const float*)d_in[0];
  const float* emb      = (const float*)d_in[2];
  const float* lin_w    = (const float*)d_in[3];
  const float* att_i    = (const float*)d_in[4];
  const float* att_j    = (const float*)d_in[5];
  const float* att_em_i = (const float*)d_in[6];
  const float* att_em_j = (const float*)d_in[7];
  const float* gnn_bias = (const float*)d_in[8];
  const float* bn1_g    = (const float*)d_in[9];
  const float* bn1_b    = (const float*)d_in[10];
  const float* bn2_g    = (const float*)d_in[11];
  const float* bn2_b    = (const float*)d_in[12];
  const float* out_w    = (const float*)d_in[13];
  const float* out_b    = (const float*)d_in[14];
  float* out = (float*)d_out;

  float* ws   = (float*)d_ws;
  float* h    = ws;                        // 4194304 floats
  float* outp = ws + 4194304;              // 4194304 (keys aliases first 1M)
  float* s_i  = ws + 8388608;              // 65536
  float* s_j  = s_i + 65536;               // 65536
  int*   topk = (int*)(s_j + 65536);       // 20480 ints
  float* acc1 = (float*)(topk + NN*KK);    // RD*128
  float* acc2 = acc1 + RD*128;             // RF*128
  float* keys = outp;                      // dead before kD writes outp

  kGC<<<256 + (BB*NN)/16, 256, 0, stream>>>(emb, data, lin_w, att_i, att_j,
                                            att_em_i, att_em_j, keys, h, s_i, s_j, acc1);
  kS<<<256, 128, 0, stream>>>(keys, topk);
  kD<<<(BB*NN)/8, 256, 0, stream>>>(h, s_i, s_j, topk, gnn_bias, outp, acc1);
  kF<<<2048, 256, 0, stream>>>(outp, emb, acc1, bn1_g, bn1_b, acc2);
  kH<<<NN/64 * 64, 256, 0, stream>>>(outp, emb, acc1, acc2, bn1_g, bn1_b,
                                     bn2_g, bn2_b, out_w, out_b, out);
}